// Round 1
// baseline (167.638 us; speedup 1.0000x reference)
//
#include <hip/hip_runtime.h>
#include <hip/hip_bf16.h>
#include <stdint.h>

// Problem constants (fixed by setup_inputs)
#define L_  32
#define B_  8
#define A_  128
#define D_  256
#define H_  8
#define HD_ 32
#define BA_ 1024
#define M_  32768   // L_*BA_

typedef float f32x4 __attribute__((ext_vector_type(4)));
typedef short s16x8 __attribute__((ext_vector_type(8)));

__device__ __forceinline__ unsigned short f2bf(float f) {
  __hip_bfloat16 h = __float2bfloat16(f);
  return __builtin_bit_cast(unsigned short, h);
}
__device__ __forceinline__ float bf2f(unsigned short u) {
  return __builtin_bit_cast(float, ((unsigned)u) << 16);
}
__device__ __forceinline__ f32x4 mfma16(s16x8 a, s16x8 b, f32x4 c) {
  return __builtin_amdgcn_mfma_f32_16x16x32_bf16(a, b, c, 0, 0, 0);
}

// K0: Wt[s][n][k] = bf16(W_s[k][n]); s: 0=Wq 1=Wk 2=Wv
__global__ void wt_kernel(const float* __restrict__ wq, const float* __restrict__ wk,
                          const float* __restrict__ wv, unsigned short* __restrict__ wt) {
  int t = blockIdx.x * 256 + threadIdx.x;           // 0..196607
  int s = t >> 16; int w = t & 65535;
  int n = w >> 8;  int k = w & 255;
  const float* W = (s == 0) ? wq : (s == 1) ? wk : wv;
  wt[t] = f2bf(W[k * 256 + n]);
}

// K1: C = X(32768x256) @ W_s(256x256), scatter to [b,h,a,l,d] bf16.
// 4 waves/block: wm in {0,1} (M halves of 64-row tile), wn in {0,1} (N halves of 256).
__global__ __launch_bounds__(256) void proj_kernel(
    const float* __restrict__ X, const unsigned short* __restrict__ wt,
    unsigned short* __restrict__ qb, unsigned short* __restrict__ kb,
    unsigned short* __restrict__ vb) {
  const int s = blockIdx.y;
  const unsigned short* Wt = wt + s * 65536;
  const int m0 = blockIdx.x * 64;
  const int tid = threadIdx.x;
  const int wid = tid >> 6, lane = tid & 63;
  const int row16 = lane & 15, grp = lane >> 4;
  const int wm = wid & 1, wn = wid >> 1;

  f32x4 acc[2][8];
  #pragma unroll
  for (int mi = 0; mi < 2; ++mi)
    #pragma unroll
    for (int ni = 0; ni < 8; ++ni) acc[mi][ni] = (f32x4){0.f, 0.f, 0.f, 0.f};

  const float* a0 = X + (size_t)(m0 + wm * 32 + row16) * 256 + grp * 8;
  const unsigned short* b0 = Wt + (size_t)(wn * 128 + row16) * 256 + grp * 8;

  #pragma unroll
  for (int kk = 0; kk < 8; ++kk) {
    const int k0 = kk * 32;
    s16x8 af[2];
    #pragma unroll
    for (int mi = 0; mi < 2; ++mi) {
      const float* ap = a0 + mi * 16 * 256 + k0;
      f32x4 f0 = *(const f32x4*)ap;
      f32x4 f1 = *(const f32x4*)(ap + 4);
      s16x8 t;
      #pragma unroll
      for (int e = 0; e < 4; ++e) {
        t[e]     = (short)f2bf(f0[e]);
        t[4 + e] = (short)f2bf(f1[e]);
      }
      af[mi] = t;
    }
    #pragma unroll
    for (int ni = 0; ni < 8; ++ni) {
      s16x8 bf = *(const s16x8*)(b0 + ni * 16 * 256 + k0);
      acc[0][ni] = mfma16(af[0], bf, acc[0][ni]);
      acc[1][ni] = mfma16(af[1], bf, acc[1][ni]);
    }
  }

  unsigned short* dst = (s == 0) ? qb : (s == 1) ? kb : vb;
  #pragma unroll
  for (int mi = 0; mi < 2; ++mi)
    #pragma unroll
    for (int ni = 0; ni < 8; ++ni)
      #pragma unroll
      for (int r = 0; r < 4; ++r) {
        int m = m0 + wm * 32 + mi * 16 + grp * 4 + r;
        int n = wn * 128 + ni * 16 + row16;
        int l = m >> 10, ba = m & 1023;
        int b = ba >> 7, a = ba & 127;
        int h = n >> 5,  d = n & 31;
        size_t di = (((size_t)(b * 8 + h) * 128 + a) * 32 + l) * 32 + d;
        dst[di] = f2bf(acc[mi][ni][r]);
      }
}

// K1b: vw1[b,h,a,l] = sum_d v*Watt[h*32+d]; vw2 with Watt[256+...]
__global__ void vw_kernel(const unsigned short* __restrict__ vb,
                          const float* __restrict__ watt,
                          float* __restrict__ vw1, float* __restrict__ vw2) {
  int row = blockIdx.x * 256 + threadIdx.x;   // (b,h,a,l) flat, 0..262143
  int h = (row >> 12) & 7;
  const unsigned short* vp = vb + (size_t)row * 32;
  const float* w1 = watt + h * 32;
  const float* w2 = watt + 256 + h * 32;
  float t1 = 0.f, t2 = 0.f;
  #pragma unroll
  for (int c = 0; c < 4; ++c) {
    s16x8 v8 = *(const s16x8*)(vp + c * 8);
    #pragma unroll
    for (int e = 0; e < 8; ++e) {
      float v = bf2f((unsigned short)v8[e]);
      int d = c * 8 + e;
      t1 += v * w1[d];
      t2 += v * w2[d];
    }
  }
  vw1[row] = t1;
  vw2[row] = t2;
}

// K2: one 64-lane block per (b,h, i-tile16, j-tile16).
// scores via mfma(K,Q): D row=i, col=j; all 32 l-values for an (i,j) are lane-local.
__global__ __launch_bounds__(64, 2) void attn_kernel(
    const unsigned short* __restrict__ qb, const unsigned short* __restrict__ kb,
    const float* __restrict__ vw1, const float* __restrict__ vw2,
    float* __restrict__ attn_out, float* __restrict__ p1, float* __restrict__ p2) {
  const int bx = blockIdx.x;                 // 4096 = 64 bh * 8 it * 8 jt
  const int jt = bx & 7, it = (bx >> 3) & 7, bh = bx >> 6;
  const int lane = threadIdx.x;
  const int row16 = lane & 15, grp = lane >> 4;
  const int ibase = it * 16, jbase = jt * 16;

  const unsigned short* kp = kb + ((size_t)bh * 128 + ibase + row16) * 1024 + grp * 8;
  const unsigned short* qp = qb + ((size_t)bh * 128 + jbase + row16) * 1024 + grp * 8;

  f32x4 acc[32];
  const f32x4 zero = {0.f, 0.f, 0.f, 0.f};
  #pragma unroll
  for (int l = 0; l < 32; ++l) {
    s16x8 kf = *(const s16x8*)(kp + l * 32);
    s16x8 qf = *(const s16x8*)(qp + l * 32);
    acc[l] = mfma16(kf, qf, zero);
  }

  // lane-local softmax over l for each of the 4 accumulator rows
  #pragma unroll
  for (int r = 0; r < 4; ++r) {
    float mx = -1e30f;
    #pragma unroll
    for (int l = 0; l < 32; ++l) {
      float sv = acc[l][r] * 0.0625f;   // 1/sqrt(256)
      acc[l][r] = sv;
      mx = fmaxf(mx, sv);
    }
    float sum = 0.f;
    #pragma unroll
    for (int l = 0; l < 32; ++l) {
      float e = __expf(acc[l][r] - mx);
      acc[l][r] = e;
      sum += e;
    }
    float inv = 1.f / sum;
    #pragma unroll
    for (int l = 0; l < 32; ++l) acc[l][r] *= inv;
  }

  // write attn + P1/P2 partials
  #pragma unroll
  for (int r = 0; r < 4; ++r) {
    const int i = ibase + grp * 4 + r;
    const int j = jbase + row16;
    float* ob = attn_out + (((size_t)bh * 128 + i) * 128 + j) * 32;
    #pragma unroll
    for (int t = 0; t < 8; ++t) {
      f32x4 w = {acc[4 * t][r], acc[4 * t + 1][r], acc[4 * t + 2][r], acc[4 * t + 3][r]};
      *(f32x4*)(ob + 4 * t) = w;
    }
    const float* v1 = vw1 + ((size_t)bh * 128 + i) * 32;
    const float* v2 = vw2 + ((size_t)bh * 128 + i) * 32;
    float t1 = 0.f, t2 = 0.f;
    #pragma unroll
    for (int l = 0; l < 32; ++l) {
      t1 += acc[l][r] * v1[l];
      t2 += acc[l][r] * v2[l];
    }
    p1[((size_t)bh * 128 + i) * 128 + j] = t1;
    p2[((size_t)bh * 128 + i) * 128 + j] = t2;
  }
}

// K3: weight[b,i,j] = tanh(sum_h P1[b,h,i,j] + sum_h P2[b,h,j,i] + b_att + 0.5) * (i!=j)
__global__ void weight_kernel(const float* __restrict__ p1, const float* __restrict__ p2,
                              const float* __restrict__ b_att, float* __restrict__ wout) {
  int t = blockIdx.x * 256 + threadIdx.x;   // 0..131071
  int b = t >> 14, i = (t >> 7) & 127, j = t & 127;
  float s = b_att[0] + 0.5f;
  #pragma unroll
  for (int h = 0; h < 8; ++h) {
    s += p1[(((size_t)b * 8 + h) * 128 + i) * 128 + j];
    s += p2[(((size_t)b * 8 + h) * 128 + j) * 128 + i];
  }
  float w = tanhf(s);
  wout[t] = (i == j) ? 0.f : w;
}

extern "C" void kernel_launch(void* const* d_in, const int* in_sizes, int n_in,
                              void* d_out, int out_size, void* d_ws, size_t ws_size,
                              hipStream_t stream) {
  const float* X    = (const float*)d_in[0];   // output (L, B*A, D)
  const float* Wk   = (const float*)d_in[1];
  const float* Wq   = (const float*)d_in[2];
  const float* Wv   = (const float*)d_in[3];
  const float* Watt = (const float*)d_in[4];   // (512,1)
  const float* b_att= (const float*)d_in[5];   // (1,)

  char* ws = (char*)d_ws;
  unsigned short* wt = (unsigned short*)ws;                              // 393216 B
  unsigned short* qb = (unsigned short*)(ws + 393216);                   // 16 MiB
  unsigned short* kb = (unsigned short*)(ws + 393216 + 16777216);
  unsigned short* vb = (unsigned short*)(ws + 393216 + 2 * 16777216);
  float* vw1 = (float*)(ws + 393216 + 3 * 16777216);                     // 1 MiB
  float* vw2 = (float*)(ws + 393216 + 3 * 16777216 + 1048576);
  float* p1  = (float*)(ws + 393216 + 3 * 16777216 + 2 * 1048576);       // 4 MiB
  float* p2  = (float*)(ws + 393216 + 3 * 16777216 + 2 * 1048576 + 4194304);

  float* attn_out = (float*)d_out;                    // 33554432 floats
  float* wout     = (float*)d_out + 33554432;         // 131072 floats

  wt_kernel<<<dim3(768), dim3(256), 0, stream>>>(Wq, Wk, Wv, wt);
  proj_kernel<<<dim3(512, 3), dim3(256), 0, stream>>>(X, wt, qb, kb, vb);
  vw_kernel<<<dim3(1024), dim3(256), 0, stream>>>(vb, Watt, vw1, vw2);
  attn_kernel<<<dim3(4096), dim3(64), 0, stream>>>(qb, kb, vw1, vw2, attn_out, p1, p2);
  weight_kernel<<<dim3(512), dim3(256), 0, stream>>>(p1, p2, b_att, wout);
}